// Round 3
// baseline (1435.025 us; speedup 1.0000x reference)
//
#include <hip/hip_runtime.h>
#include <hip/hip_bf16.h>

#define NNODES 32
#define TSTEPS 49
#define NEDGE  992
#define ROWS_E 7936     // B*E
#define ROWS_OUT 12544  // B*T*N
#define EPSV 1e-5f

typedef __hip_bfloat16 bf16;
typedef __attribute__((ext_vector_type(8))) short bf16x8;
typedef __attribute__((ext_vector_type(4))) float f32x4;

__device__ inline float eluf(float x){ return x > 0.f ? x : (__expf(x) - 1.f); }
__device__ inline float bfu2f(unsigned short u){ unsigned v = ((unsigned)u) << 16; return *reinterpret_cast<float*>(&v); }

__device__ inline bf16x8 addrelu_pack(bf16x8 s, bf16x8 r){
  bf16x8 out;
  #pragma unroll
  for (int i = 0; i < 8; i++){
    unsigned ss = ((unsigned)(unsigned short)s[i]) << 16;
    unsigned rr = ((unsigned)(unsigned short)r[i]) << 16;
    float v = *reinterpret_cast<float*>(&ss) + *reinterpret_cast<float*>(&rr);
    v = fmaxf(v, 0.f);
    __hip_bfloat16 h = __float2bfloat16(v);
    out[i] = *reinterpret_cast<short*>(&h);
  }
  return out;
}

// ---------------- weight prep: transpose + bf16 convert + bias builds ----------------
__global__ void prep_weights(const float* e2w1, const float* e2w2, const float* e4w1, const float* e4w2,
                             const float* mw2, const float* ow1, const float* ow2,
                             const float* e2b1, const float* e4b1,
                             bf16* w2abT, bf16* w2bT, bf16* w4abT, bf16* w4cT, bf16* w4bT,
                             bf16* mw2T, bf16* ow1T, bf16* ow2T,
                             float* bias2, float* bias4, float* zerob){
  int i = blockIdx.x*256 + threadIdx.x;
  if (i < 131072){ int n=i>>8, c=i&255;
    w2abT[i] = __float2bfloat16(n<256 ? e2w1[c*256+n] : e2w1[(256+c)*256 + (n-256)]); return;} i-=131072;
  if (i < 65536){ int n=i>>8,c=i&255; w2bT[i]=__float2bfloat16(e2w2[c*256+n]); return;} i-=65536;
  if (i < 131072){ int n=i>>8,c=i&255;
    w4abT[i]=__float2bfloat16(n<256 ? e4w1[c*256+n] : e4w1[(256+c)*256+(n-256)]); return;} i-=131072;
  if (i < 65536){ int n=i>>8,c=i&255; w4cT[i]=__float2bfloat16(e4w1[(512+c)*256+n]); return;} i-=65536;
  if (i < 65536){ int n=i>>8,c=i&255; w4bT[i]=__float2bfloat16(e4w2[c*256+n]); return;} i-=65536;
  if (i < 262144){ int k=i>>16, r=i&65535; int n=r>>8,c=r&255;
    mw2T[i]=__float2bfloat16(mw2[(k*256+c)*256+n]); return;} i-=262144;
  if (i < 73728){ int n=i/288, c=i%288;
    ow1T[i]= (c<260)?__float2bfloat16(ow1[c*256+n]):__float2bfloat16(0.f); return;} i-=73728;
  if (i < 65536){ int n=i>>8,c=i&255; ow2T[i]=__float2bfloat16(ow2[c*256+n]); return;} i-=65536;
  if (i < 512){ bias2[i] = (i<256)?e2b1[i]:0.f; return;} i-=512;
  if (i < 512){ bias4[i] = (i<256)?e4b1[i]:0.f; return;} i-=512;
  if (i < 256){ zerob[i]=0.f; return; }
}

// ---------------- small 2-layer ELU MLP (256 rows), fp32 VALU ----------------
template<int KIN>
__global__ void small_mlp(const float* __restrict__ X, const float* __restrict__ w1, const float* __restrict__ b1,
                          const float* __restrict__ w2, const float* __restrict__ b2, float* __restrict__ H){
  __shared__ float xs[KIN];
  __shared__ float h1[256];
  int r = blockIdx.x, f = threadIdx.x;
  for (int c = f; c < KIN; c += 256) xs[c] = X[(size_t)r*KIN + c];
  __syncthreads();
  float acc = b1[f];
  for (int c = 0; c < KIN; c++) acc = fmaf(xs[c], w1[c*256+f], acc);
  h1[f] = eluf(acc);
  __syncthreads();
  float a2 = b2[f];
  for (int c = 0; c < 256; c++) a2 = fmaf(h1[c], w2[c*256+f], a2);
  H[(size_t)r*256 + f] = eluf(a2);
}

// BN over 256 rows (single block); writes bf16 normalized
__global__ void bn_small(const float* __restrict__ H, const float* __restrict__ g, const float* __restrict__ be,
                         bf16* __restrict__ Xout){
  int f = threadIdx.x;
  float s = 0.f, s2 = 0.f;
  for (int r = 0; r < 256; r++){ float v = H[r*256+f]; s += v; s2 += v*v; }
  float m = s * (1.f/256.f), var = s2 * (1.f/256.f) - m*m;
  float sc = g[f] * rsqrtf(var + EPSV), sh = be[f] - m*sc;
  for (int r = 0; r < 256; r++) Xout[r*256+f] = __float2bfloat16(H[r*256+f]*sc + sh);
}

// ---------------- generic MFMA GEMM: Y = act(A @ W + b) ----------------
// A: bf16 MxK row-major; WT: bf16 NCOLSxK row-major. Optional fused BN-stats partials.
template<int K, int NCOLS, int ACT, bool OBF, int MT, bool STATS>
__global__ __launch_bounds__(256,4) void gemm_mfma(const bf16* __restrict__ A, const bf16* __restrict__ WT,
                                                   const float* __restrict__ bias, void* __restrict__ Y,
                                                   float* __restrict__ part){
  constexpr int NTW = NCOLS/64;           // n-tiles per wave
  int mb = blockIdx.x;
  int tid = threadIdx.x;
  int w = tid >> 6, l = tid & 63, l15 = l & 15, lq = l >> 4;
  f32x4 acc[MT/16][NTW];
  #pragma unroll
  for (int m = 0; m < MT/16; m++)
    #pragma unroll
    for (int nt = 0; nt < NTW; nt++) acc[m][nt] = (f32x4){0.f,0.f,0.f,0.f};
  const bf16* Ab = A + (size_t)mb*MT*K;
  int nw = w*(NCOLS/4);
  for (int s = 0; s < K/32; s++){
    int c0 = s*32 + lq*8;
    bf16x8 bfr[NTW];
    #pragma unroll
    for (int nt = 0; nt < NTW; nt++){
      int fcol = nw + nt*16 + l15;
      bfr[nt] = *reinterpret_cast<const bf16x8*>(WT + (size_t)fcol*K + c0);
    }
    #pragma unroll
    for (int m = 0; m < MT/16; m++){
      bf16x8 afr = *reinterpret_cast<const bf16x8*>(Ab + (size_t)(m*16 + l15)*K + c0);
      #pragma unroll
      for (int nt = 0; nt < NTW; nt++)
        acc[m][nt] = __builtin_amdgcn_mfma_f32_16x16x32_bf16(afr, bfr[nt], acc[m][nt], 0, 0, 0);
    }
  }
  #pragma unroll
  for (int nt = 0; nt < NTW; nt++){
    int fcol = nw + nt*16 + l15;
    float bv = bias[fcol];
    float cs = 0.f, cs2 = 0.f;
    #pragma unroll
    for (int m = 0; m < MT/16; m++){
      #pragma unroll
      for (int v = 0; v < 4; v++){
        int row = mb*MT + m*16 + lq*4 + v;
        float val = acc[m][nt][v] + bv;
        if (ACT == 1) val = fmaxf(val, 0.f);
        else if (ACT == 2) val = eluf(val);
        if (OBF) ((bf16*)Y)[(size_t)row*NCOLS + fcol] = __float2bfloat16(val);
        else     ((float*)Y)[(size_t)row*NCOLS + fcol] = val;
        if (STATS){ cs += val; cs2 += val*val; }
      }
    }
    if (STATS){
      cs  += __shfl_xor(cs, 16);  cs  += __shfl_xor(cs, 32);
      cs2 += __shfl_xor(cs2, 16); cs2 += __shfl_xor(cs2, 32);
      if (l < 16){ part[(size_t)mb*512 + fcol] = cs; part[(size_t)mb*512 + 256 + fcol] = cs2; }
    }
  }
}

// ---------------- edge combiners (replace gathers + big-K GEMMs) ----------------
// Y[row] = elu(SR[send][0:256] + SR[recv][256:512])  (bf16 out), rows = B*E
__global__ void combine2(const bf16* __restrict__ SR, bf16* __restrict__ Y){
  int i = blockIdx.x*256 + threadIdx.x;   // 7936*32 chunks
  int row = i >> 5, c8 = (i & 31)*8;
  int b = row / NEDGE, e = row % NEDGE;
  int rc = e / 31, jj = e % 31;
  int sn = jj + (jj >= rc);
  bf16x8 s8 = *reinterpret_cast<const bf16x8*>(SR + (size_t)(b*NNODES + sn)*512 + c8);
  bf16x8 r8 = *reinterpret_cast<const bf16x8*>(SR + (size_t)(b*NNODES + rc)*512 + 256 + c8);
  bf16x8 o;
  #pragma unroll
  for (int k = 0; k < 8; k++){
    float v = bfu2f((unsigned short)s8[k]) + bfu2f((unsigned short)r8[k]);
    v = eluf(v);
    __hip_bfloat16 h = __float2bfloat16(v);
    o[k] = *reinterpret_cast<short*>(&h);
  }
  *reinterpret_cast<bf16x8*>(Y + (size_t)row*256 + c8) = o;
}

// Y[row] = elu(SR[send][0:256] + SR[recv][256:512] + Z[row])  (bf16 out)
__global__ void combine4(const bf16* __restrict__ SR, const float* __restrict__ Z, bf16* __restrict__ Y){
  int i = blockIdx.x*256 + threadIdx.x;
  int row = i >> 5, c8 = (i & 31)*8;
  int b = row / NEDGE, e = row % NEDGE;
  int rc = e / 31, jj = e % 31;
  int sn = jj + (jj >= rc);
  bf16x8 s8 = *reinterpret_cast<const bf16x8*>(SR + (size_t)(b*NNODES + sn)*512 + c8);
  bf16x8 r8 = *reinterpret_cast<const bf16x8*>(SR + (size_t)(b*NNODES + rc)*512 + 256 + c8);
  const float* zp = Z + (size_t)row*256 + c8;
  float4 z0 = *reinterpret_cast<const float4*>(zp);
  float4 z1 = *reinterpret_cast<const float4*>(zp+4);
  float zz[8] = {z0.x,z0.y,z0.z,z0.w,z1.x,z1.y,z1.z,z1.w};
  bf16x8 o;
  #pragma unroll
  for (int k = 0; k < 8; k++){
    float v = bfu2f((unsigned short)s8[k]) + bfu2f((unsigned short)r8[k]) + zz[k];
    v = eluf(v);
    __hip_bfloat16 h = __float2bfloat16(v);
    o[k] = *reinterpret_cast<short*>(&h);
  }
  *reinterpret_cast<bf16x8*>(Y + (size_t)row*256 + c8) = o;
}

// ---------------- batchnorm finalize/apply ----------------
__global__ void bn_finalize(const float* __restrict__ part, int nb, const float* __restrict__ g,
                            const float* __restrict__ be, float* __restrict__ prm, float nrows){
  int f = threadIdx.x;
  float s = 0.f, s2 = 0.f;
  for (int i = 0; i < nb; i++){ s += part[(size_t)i*512+f]; s2 += part[(size_t)i*512+256+f]; }
  float m = s / nrows, var = s2 / nrows - m*m;
  float sc = g[f] * rsqrtf(var + EPSV);
  prm[f] = sc; prm[256+f] = be[f] - m*sc;
}
__global__ void bn_apply(const float* __restrict__ Y, const float* __restrict__ prm, bf16* __restrict__ X){
  int i = blockIdx.x*256 + threadIdx.x;    // 7936*32 chunks of 8
  int c8 = (i & 31)*8;
  const float* yp = Y + (size_t)i*8;
  float4 a0 = *reinterpret_cast<const float4*>(yp);
  float4 a1 = *reinterpret_cast<const float4*>(yp+4);
  float4 s0 = *reinterpret_cast<const float4*>(prm + c8);
  float4 s1 = *reinterpret_cast<const float4*>(prm + c8 + 4);
  float4 h0 = *reinterpret_cast<const float4*>(prm + 256 + c8);
  float4 h1 = *reinterpret_cast<const float4*>(prm + 256 + c8 + 4);
  float vals[8] = {a0.x*s0.x+h0.x, a0.y*s0.y+h0.y, a0.z*s0.z+h0.z, a0.w*s0.w+h0.w,
                   a1.x*s1.x+h1.x, a1.y*s1.y+h1.y, a1.z*s1.z+h1.z, a1.w*s1.w+h1.w};
  bf16x8 o;
  #pragma unroll
  for (int k = 0; k < 8; k++){
    __hip_bfloat16 h = __float2bfloat16(vals[k]);
    o[k] = *reinterpret_cast<short*>(&h);
  }
  *reinterpret_cast<bf16x8*>(X + (size_t)i*8) = o;
}

// ---------------- incoming = segment-sum over 31 edges / N ----------------
__global__ void seg_incoming(const bf16* __restrict__ X2, float* __restrict__ inc){
  int bn = blockIdx.x; int b = bn >> 5, n = bn & 31;
  int f = threadIdx.x;
  const bf16* p = X2 + (size_t)(b*NEDGE + n*31)*256 + f;
  float s = 0.f;
  for (int j = 0; j < 31; j++) s += __bfloat162float(p[j*256]);
  inc[bn*256 + f] = s * (1.f/32.f);
}

// ---------------- fc + softmax (prob out, rel_type to ws) ----------------
__global__ void fc_softmax(const bf16* __restrict__ X4, const float* __restrict__ fcw, const float* __restrict__ fcb,
                           const float* __restrict__ gumbel, float* __restrict__ prob_out, float* __restrict__ rt){
  int r = blockIdx.x*256 + threadIdx.x;
  if (r >= ROWS_E) return;
  float l0 = fcb[0], l1 = fcb[1], l2 = fcb[2], l3 = fcb[3];
  const bf16* xr = X4 + (size_t)r*256;
  for (int c = 0; c < 256; c += 8){
    uint4 u = *reinterpret_cast<const uint4*>(xr + c);
    unsigned uu[4] = {u.x, u.y, u.z, u.w};
    #pragma unroll
    for (int q = 0; q < 4; q++){
      float x0 = bfu2f((unsigned short)(uu[q] & 0xffff));
      float x1 = bfu2f((unsigned short)(uu[q] >> 16));
      int cc = c + 2*q;
      float4 w0 = *reinterpret_cast<const float4*>(fcw + cc*4);
      float4 w1 = *reinterpret_cast<const float4*>(fcw + (cc+1)*4);
      l0 += x0*w0.x + x1*w1.x; l1 += x0*w0.y + x1*w1.y;
      l2 += x0*w0.z + x1*w1.z; l3 += x0*w0.w + x1*w1.w;
    }
  }
  float mx = fmaxf(fmaxf(l0,l1), fmaxf(l2,l3));
  float e0 = __expf(l0-mx), e1 = __expf(l1-mx), e2 = __expf(l2-mx), e3 = __expf(l3-mx);
  float inv = 1.f / (e0+e1+e2+e3);
  prob_out[(size_t)r*4+0] = e0*inv; prob_out[(size_t)r*4+1] = e1*inv;
  prob_out[(size_t)r*4+2] = e2*inv; prob_out[(size_t)r*4+3] = e3*inv;
  float4 gv = *reinterpret_cast<const float4*>(gumbel + (size_t)r*4);
  float t0 = (l0+gv.x)*2.f, t1 = (l1+gv.y)*2.f, t2 = (l2+gv.z)*2.f, t3 = (l3+gv.w)*2.f;
  float mx2 = fmaxf(fmaxf(t0,t1), fmaxf(t2,t3));
  float f0 = __expf(t0-mx2), f1 = __expf(t1-mx2), f2 = __expf(t2-mx2), f3 = __expf(t3-mx2);
  float inv2 = 1.f / (f0+f1+f2+f3);
  rt[(size_t)r*4+0] = f0*inv2; rt[(size_t)r*4+1] = f1*inv2;
  rt[(size_t)r*4+2] = f2*inv2; rt[(size_t)r*4+3] = f3*inv2;
}

// ---------------- fused decoder message passing v3 ----------------
// block: one (b,t) x 2 receivers (64 padded edge-rows). Layer-1 S/R computed IN-BLOCK
// into LDS (S: all 32 nodes, swizzled; R: 2 receivers). Wave-per-m fragment-direct MFMA.
// Analytic edge indexing: recv i, slot j -> send = j + (j>=i).
__global__ __launch_bounds__(256,3) void decoder_msg(
    const float* __restrict__ data, const float* __restrict__ rt,
    const float* __restrict__ mw1, const float* __restrict__ mb1,
    const bf16* __restrict__ mw2T, const float* __restrict__ mb2,
    bf16* __restrict__ Aaug){
  __shared__ __align__(16) float xn[32][4];
  __shared__ __align__(16) short Ssw[32*256];   // 16KB, xor-swizzled by node
  __shared__ __align__(16) short Rsw[2*256];    // 1KB
  __shared__ __align__(16) float rts_s[64][4];
  __shared__ __align__(16) float aggl[4][256];  // per-wave partial agg
  int bx = blockIdx.x;
  int bt = bx >> 4, rg2 = bx & 15;
  int b = bt / TSTEPS, t = bt % TSTEPS;
  int n0 = rg2*2;
  int tid = threadIdx.x;
  int w = tid >> 6, l = tid & 63, l15 = l & 15, lq = l >> 4;

  if (tid < 32){
    *reinterpret_cast<float4*>(&xn[tid][0]) =
        *reinterpret_cast<const float4*>(data + ((size_t)(b*NNODES + tid)*TSTEPS + t)*4);
  } else if (tid >= 64 && tid < 128){
    int r = tid - 64;
    int n = n0 + (r>>5), j = r&31;
    float4 rv = make_float4(0.f,0.f,0.f,0.f);
    if (j < 31) rv = *reinterpret_cast<const float4*>(rt + ((size_t)(b*NEDGE + n*31 + j))*4);
    *reinterpret_cast<float4*>(&rts_s[r][0]) = rv;
  }
  for (int i = tid; i < 1024; i += 256) ((float*)aggl)[i] = 0.f;
  __syncthreads();

  // per-lane A-fragment geometry (invariant across kk)
  int arow = w*16 + l15;
  int rgrp = arow >> 5;
  int aj = arow & 31;
  int recvn = n0 + rgrp;
  bool avalid = (aj < 31);
  int snd = avalid ? (aj + (aj >= recvn)) : 0;
  int sswz = (snd & 7) << 4;

  for (int kk = 1; kk < 4; kk++){
    if (kk > 1) __syncthreads();
    { // build S (32 nodes) + R (2 receivers), this thread owns column c = tid
      float wr0 = mw1[(size_t)(kk*8+0)*256 + tid], wr1 = mw1[(size_t)(kk*8+1)*256 + tid],
            wr2 = mw1[(size_t)(kk*8+2)*256 + tid], wr3 = mw1[(size_t)(kk*8+3)*256 + tid],
            wr4 = mw1[(size_t)(kk*8+4)*256 + tid], wr5 = mw1[(size_t)(kk*8+5)*256 + tid],
            wr6 = mw1[(size_t)(kk*8+6)*256 + tid], wr7 = mw1[(size_t)(kk*8+7)*256 + tid];
      float bs = mb1[kk*256 + tid];
      #pragma unroll 8
      for (int nd = 0; nd < 32; nd++){
        float4 x = *reinterpret_cast<float4*>(&xn[nd][0]);
        float sv = fmaf(x.x,wr0, fmaf(x.y,wr1, fmaf(x.z,wr2, fmaf(x.w,wr3, bs))));
        __hip_bfloat16 h = __float2bfloat16(sv);
        *reinterpret_cast<short*>(reinterpret_cast<char*>(Ssw) + nd*512 + ((2*tid) ^ ((nd&7)<<4))) =
            *reinterpret_cast<short*>(&h);
      }
      float4 xa = *reinterpret_cast<float4*>(&xn[n0][0]);
      float rva = fmaf(xa.x,wr4, fmaf(xa.y,wr5, fmaf(xa.z,wr6, xa.w*wr7)));
      __hip_bfloat16 ha = __float2bfloat16(rva);
      Rsw[tid] = *reinterpret_cast<short*>(&ha);
      float4 xb = *reinterpret_cast<float4*>(&xn[n0+1][0]);
      float rvb = fmaf(xb.x,wr4, fmaf(xb.y,wr5, fmaf(xb.z,wr6, xb.w*wr7)));
      __hip_bfloat16 hb = __float2bfloat16(rvb);
      Rsw[256 + tid] = *reinterpret_cast<short*>(&hb);
    }
    __syncthreads();

    // A fragments for this wave's 16 rows (built once, reused by 16 n-tiles)
    bf16x8 afr[8];
    #pragma unroll
    for (int s = 0; s < 8; s++){
      int c0 = s*32 + lq*8;
      bf16x8 svv = *reinterpret_cast<const bf16x8*>(
          reinterpret_cast<const char*>(Ssw) + snd*512 + ((2*c0) ^ sswz));
      bf16x8 rvv = *reinterpret_cast<const bf16x8*>(
          reinterpret_cast<const char*>(Rsw) + rgrp*512 + 2*c0);
      afr[s] = avalid ? addrelu_pack(svv, rvv) : (bf16x8){0,0,0,0,0,0,0,0};
    }

    f32x4 acc[16];
    #pragma unroll
    for (int nt = 0; nt < 16; nt++) acc[nt] = (f32x4){0.f,0.f,0.f,0.f};
    const bf16* bbase = mw2T + (size_t)kk*65536 + l15*256 + lq*8;
    #pragma unroll
    for (int s = 0; s < 8; s++){
      #pragma unroll
      for (int nt = 0; nt < 16; nt++){
        bf16x8 bfr = *reinterpret_cast<const bf16x8*>(bbase + nt*4096 + s*32);
        acc[nt] = __builtin_amdgcn_mfma_f32_16x16x32_bf16(afr[s], bfr, acc[nt], 0, 0, 0);
      }
    }

    // epilogue: relu(+b2), weight by rel_type, column-sum over this wave's 16 rows
    float rw[4];
    #pragma unroll
    for (int v = 0; v < 4; v++) rw[v] = rts_s[w*16 + lq*4 + v][kk];
    #pragma unroll
    for (int nt = 0; nt < 16; nt++){
      int fcol = nt*16 + l15;
      float bv = mb2[kk*256 + fcol];
      float ssum = 0.f;
      #pragma unroll
      for (int v = 0; v < 4; v++){
        float msg = fmaxf(acc[nt][v] + bv, 0.f);
        ssum += msg * rw[v];
      }
      ssum += __shfl_xor(ssum, 16);
      ssum += __shfl_xor(ssum, 32);
      if (l < 16) aggl[w][fcol] += ssum;
    }
  }
  __syncthreads();

  // write aug rows: [data(4) | agg(256) | pad(28)] bf16, K=288
  for (int i = tid; i < 2*288; i += 256){
    int g = i / 288, c = i % 288;
    float val;
    if (c < 4)        val = xn[n0+g][c];
    else if (c < 260) val = aggl[2*g][c-4] + aggl[2*g+1][c-4];
    else              val = 0.f;
    Aaug[(size_t)(bt*NNODES + n0 + g)*288 + c] = __float2bfloat16(val);
  }
}

// ---------------- final: p3 = P2 @ ow3 + ob3 ; out = data + p3 (t<48) ----------------
__global__ void final_out(const bf16* __restrict__ P2, const float* __restrict__ ow3,
                          const float* __restrict__ ob3, const float* __restrict__ data,
                          float* __restrict__ out){
  int r = blockIdx.x*256 + threadIdx.x;
  if (r >= ROWS_OUT) return;
  int bt = r >> 5, n = r & 31;
  int b = bt / TSTEPS, t = bt % TSTEPS;
  float a0 = ob3[0], a1 = ob3[1], a2 = ob3[2], a3 = ob3[3];
  const bf16* pr = P2 + (size_t)r*256;
  for (int c = 0; c < 256; c += 8){
    uint4 u = *reinterpret_cast<const uint4*>(pr + c);
    unsigned uu[4] = {u.x, u.y, u.z, u.w};
    #pragma unroll
    for (int q = 0; q < 4; q++){
      float x0 = bfu2f((unsigned short)(uu[q] & 0xffff));
      float x1 = bfu2f((unsigned short)(uu[q] >> 16));
      int cc = c + 2*q;
      float4 w0 = *reinterpret_cast<const float4*>(ow3 + cc*4);
      float4 w1 = *reinterpret_cast<const float4*>(ow3 + (cc+1)*4);
      a0 += x0*w0.x + x1*w1.x; a1 += x0*w0.y + x1*w1.y;
      a2 += x0*w0.z + x1*w1.z; a3 += x0*w0.w + x1*w1.w;
    }
  }
  if (t < TSTEPS-1){
    float4 dv = *reinterpret_cast<const float4*>(data + ((size_t)(b*NNODES + n)*TSTEPS + t)*4);
    float4 o; o.x = dv.x + a0; o.y = dv.y + a1; o.z = dv.z + a2; o.w = dv.w + a3;
    *reinterpret_cast<float4*>(out + ((size_t)(b*NNODES + n)*(TSTEPS-1) + t)*4) = o;
  }
}

// ---------------- launcher ----------------
extern "C" void kernel_launch(void* const* d_in, const int* in_sizes, int n_in,
                              void* d_out, int out_size, void* d_ws, size_t ws_size,
                              hipStream_t stream){
  const float* data    = (const float*)d_in[0];
  const float* gumbel  = (const float*)d_in[1];
  const float* e1_w1=(const float*)d_in[4],  *e1_b1=(const float*)d_in[5],
             * e1_w2=(const float*)d_in[6],  *e1_b2=(const float*)d_in[7],
             * e1_g =(const float*)d_in[8],  *e1_be=(const float*)d_in[9];
  const float* e2_w1=(const float*)d_in[10], *e2_b1=(const float*)d_in[11],
             * e2_w2=(const float*)d_in[12], *e2_b2=(const float*)d_in[13],
             * e2_g =(const float*)d_in[14], *e2_be=(const float*)d_in[15];
  const float* e3_w1=(const float*)d_in[16], *e3_b1=(const float*)d_in[17],
             * e3_w2=(const float*)d_in[18], *e3_b2=(const float*)d_in[19],
             * e3_g =(const float*)d_in[20], *e3_be=(const float*)d_in[21];
  const float* e4_w1=(const float*)d_in[22], *e4_b1=(const float*)d_in[23],
             * e4_w2=(const float*)d_in[24], *e4_b2=(const float*)d_in[25],
             * e4_g =(const float*)d_in[26], *e4_be=(const float*)d_in[27];
  const float* fc_w=(const float*)d_in[28], *fc_b=(const float*)d_in[29];
  const float* mw1=(const float*)d_in[30], *mb1=(const float*)d_in[31];
  const float* mw2=(const float*)d_in[32], *mb2=(const float*)d_in[33];
  const float* ow1=(const float*)d_in[34], *ob1=(const float*)d_in[35];
  const float* ow2=(const float*)d_in[36], *ob2=(const float*)d_in[37];
  const float* ow3=(const float*)d_in[38], *ob3=(const float*)d_in[39];

  char* ws = (char*)d_ws;
  size_t off = 0;
  auto alloc = [&](size_t bytes)->void*{ void* p = ws + off; off = (off + bytes + 255) & ~(size_t)255; return p; };
  bf16* W2ABT= (bf16*)alloc((size_t)131072*2);
  bf16* W2BT = (bf16*)alloc((size_t)65536*2);
  bf16* W4ABT= (bf16*)alloc((size_t)131072*2);
  bf16* W4CT = (bf16*)alloc((size_t)65536*2);
  bf16* W4BT = (bf16*)alloc((size_t)65536*2);
  bf16* MW2T = (bf16*)alloc((size_t)262144*2);
  bf16* OW1T = (bf16*)alloc((size_t)73728*2);
  bf16* OW2T = (bf16*)alloc((size_t)65536*2);
  float* BIAS2=(float*)alloc((size_t)512*4);
  float* BIAS4=(float*)alloc((size_t)512*4);
  float* ZEROB=(float*)alloc((size_t)256*4);
  bf16* X1   = (bf16*)alloc((size_t)65536*2);
  float* HS  = (float*)alloc((size_t)65536*4);
  bf16* X3   = (bf16*)alloc((size_t)65536*2);
  bf16* SR2  = (bf16*)alloc((size_t)131072*2);
  bf16* SR4  = (bf16*)alloc((size_t)131072*2);
  float* Z4  = (float*)alloc((size_t)7936*256*4);
  bf16* YBF  = (bf16*)alloc((size_t)12544*256*2);
  float* YF32= (float*)alloc((size_t)7936*256*4);
  bf16* X2   = (bf16*)alloc((size_t)7936*256*2);
  bf16* X4   = (bf16*)alloc((size_t)7936*256*2);
  bf16* P2   = (bf16*)alloc((size_t)12544*256*2);
  float* INC = (float*)alloc((size_t)65536*4);
  float* RT  = (float*)alloc((size_t)7936*4*4);
  float* PART= (float*)alloc((size_t)248*512*4);
  float* PRM = (float*)alloc((size_t)512*4);
  bf16* AAUG = (bf16*)alloc((size_t)12544*288*2);

  float* out = (float*)d_out;
  float* prob_out = out + 49152;

  prep_weights<<<3365,256,0,stream>>>(e2_w1,e2_w2,e4_w1,e4_w2,mw2,ow1,ow2,e2_b1,e4_b1,
                                      W2ABT,W2BT,W4ABT,W4CT,W4BT,MW2T,OW1T,OW2T,BIAS2,BIAS4,ZEROB);
  small_mlp<196><<<256,256,0,stream>>>(data, e1_w1,e1_b1,e1_w2,e1_b2, HS);
  bn_small<<<1,256,0,stream>>>(HS, e1_g, e1_be, X1);
  gemm_mfma<256,512,0,true,32,false><<<8,256,0,stream>>>(X1, W2ABT, BIAS2, SR2, nullptr);
  combine2<<<992,256,0,stream>>>(SR2, YBF);
  gemm_mfma<256,256,2,false,32,true><<<248,256,0,stream>>>(YBF, W2BT, e2_b2, YF32, PART);
  bn_finalize<<<1,256,0,stream>>>(PART, 248, e2_g, e2_be, PRM, 7936.f);
  bn_apply<<<992,256,0,stream>>>(YF32, PRM, X2);
  seg_incoming<<<256,256,0,stream>>>(X2, INC);
  small_mlp<256><<<256,256,0,stream>>>(INC, e3_w1,e3_b1,e3_w2,e3_b2, HS);
  bn_small<<<1,256,0,stream>>>(HS, e3_g, e3_be, X3);
  gemm_mfma<256,512,0,true,32,false><<<8,256,0,stream>>>(X3, W4ABT, BIAS4, SR4, nullptr);
  gemm_mfma<256,256,0,false,32,false><<<248,256,0,stream>>>(X2, W4CT, ZEROB, Z4, nullptr);
  combine4<<<992,256,0,stream>>>(SR4, Z4, YBF);
  gemm_mfma<256,256,2,false,32,true><<<248,256,0,stream>>>(YBF, W4BT, e4_b2, YF32, PART);
  bn_finalize<<<1,256,0,stream>>>(PART, 248, e4_g, e4_be, PRM, 7936.f);
  bn_apply<<<992,256,0,stream>>>(YF32, PRM, X4);
  fc_softmax<<<31,256,0,stream>>>(X4, fc_w, fc_b, gumbel, prob_out, RT);
  decoder_msg<<<6272,256,0,stream>>>(data, RT, mw1, mb1, MW2T, mb2, AAUG);
  gemm_mfma<288,256,1,true,32,false><<<392,256,0,stream>>>(AAUG, OW1T, ob1, YBF, nullptr);
  gemm_mfma<256,256,1,true,32,false><<<392,256,0,stream>>>(YBF, OW2T, ob2, P2, nullptr);
  final_out<<<49,256,0,stream>>>(P2, ow3, ob3, data, out);
}

// Round 4
// 626.356 us; speedup vs baseline: 2.2911x; 2.2911x over previous
//
#include <hip/hip_runtime.h>
#include <hip/hip_bf16.h>

#define NNODES 32
#define TSTEPS 49
#define NEDGE  992
#define ROWS_E 7936     // B*E
#define ROWS_OUT 12544  // B*T*N
#define EPSV 1e-5f

typedef __hip_bfloat16 bf16;
typedef __attribute__((ext_vector_type(8))) short bf16x8;
typedef __attribute__((ext_vector_type(4))) float f32x4;

__device__ inline float eluf(float x){ return x > 0.f ? x : (__expf(x) - 1.f); }
__device__ inline float bfu2f(unsigned short u){ unsigned v = ((unsigned)u) << 16; return *reinterpret_cast<float*>(&v); }
__device__ inline unsigned pack_bf16(float a, float b){
  __hip_bfloat16 ha = __float2bfloat16(a), hb = __float2bfloat16(b);
  unsigned short ua = *reinterpret_cast<unsigned short*>(&ha);
  unsigned short ub = *reinterpret_cast<unsigned short*>(&hb);
  return (unsigned)ua | ((unsigned)ub << 16);
}

// ---------------- weight prep: transpose + bf16 convert + bias builds ----------------
__global__ void prep_weights(const float* e2w1, const float* e2w2, const float* e4w1, const float* e4w2,
                             const float* mw2, const float* ow1, const float* ow2,
                             const float* e2b1, const float* e4b1,
                             bf16* w2abT, bf16* w2bT, bf16* w4abT, bf16* w4cT, bf16* w4bT,
                             bf16* mw2T, bf16* ow1T, bf16* ow2T,
                             float* bias2, float* bias4, float* zerob){
  int i = blockIdx.x*256 + threadIdx.x;
  if (i < 131072){ int n=i>>8, c=i&255;
    w2abT[i] = __float2bfloat16(n<256 ? e2w1[c*256+n] : e2w1[(256+c)*256 + (n-256)]); return;} i-=131072;
  if (i < 65536){ int n=i>>8,c=i&255; w2bT[i]=__float2bfloat16(e2w2[c*256+n]); return;} i-=65536;
  if (i < 131072){ int n=i>>8,c=i&255;
    w4abT[i]=__float2bfloat16(n<256 ? e4w1[c*256+n] : e4w1[(256+c)*256+(n-256)]); return;} i-=131072;
  if (i < 65536){ int n=i>>8,c=i&255; w4cT[i]=__float2bfloat16(e4w1[(512+c)*256+n]); return;} i-=65536;
  if (i < 65536){ int n=i>>8,c=i&255; w4bT[i]=__float2bfloat16(e4w2[c*256+n]); return;} i-=65536;
  if (i < 262144){ int k=i>>16, r=i&65535; int n=r>>8,c=r&255;
    mw2T[i]=__float2bfloat16(mw2[(k*256+c)*256+n]); return;} i-=262144;
  if (i < 73728){ int n=i/288, c=i%288;
    ow1T[i]= (c<260)?__float2bfloat16(ow1[c*256+n]):__float2bfloat16(0.f); return;} i-=73728;
  if (i < 65536){ int n=i>>8,c=i&255; ow2T[i]=__float2bfloat16(ow2[c*256+n]); return;} i-=65536;
  if (i < 512){ bias2[i] = (i<256)?e2b1[i]:0.f; return;} i-=512;
  if (i < 512){ bias4[i] = (i<256)?e4b1[i]:0.f; return;} i-=512;
  if (i < 256){ zerob[i]=0.f; return; }
}

// ---------------- small 2-layer ELU MLP (256 rows), fp32 VALU ----------------
template<int KIN>
__global__ void small_mlp(const float* __restrict__ X, const float* __restrict__ w1, const float* __restrict__ b1,
                          const float* __restrict__ w2, const float* __restrict__ b2, float* __restrict__ H){
  __shared__ float xs[KIN];
  __shared__ float h1[256];
  int r = blockIdx.x, f = threadIdx.x;
  for (int c = f; c < KIN; c += 256) xs[c] = X[(size_t)r*KIN + c];
  __syncthreads();
  float acc = b1[f];
  for (int c = 0; c < KIN; c++) acc = fmaf(xs[c], w1[c*256+f], acc);
  h1[f] = eluf(acc);
  __syncthreads();
  float a2 = b2[f];
  for (int c = 0; c < 256; c++) a2 = fmaf(h1[c], w2[c*256+f], a2);
  H[(size_t)r*256 + f] = eluf(a2);
}

// BN over 256 rows (single block); writes bf16 normalized
__global__ void bn_small(const float* __restrict__ H, const float* __restrict__ g, const float* __restrict__ be,
                         bf16* __restrict__ Xout){
  int f = threadIdx.x;
  float s = 0.f, s2 = 0.f;
  for (int r = 0; r < 256; r++){ float v = H[r*256+f]; s += v; s2 += v*v; }
  float m = s * (1.f/256.f), var = s2 * (1.f/256.f) - m*m;
  float sc = g[f] * rsqrtf(var + EPSV), sh = be[f] - m*sc;
  for (int r = 0; r < 256; r++) Xout[r*256+f] = __float2bfloat16(H[r*256+f]*sc + sh);
}

// ---------------- generic MFMA GEMM: Y = act(A @ W + b) ----------------
// A: bf16 MxK row-major; WT: bf16 NCOLSxK row-major. Optional fused BN-stats partials.
template<int K, int NCOLS, int ACT, bool OBF, int MT, bool STATS>
__global__ __launch_bounds__(256,4) void gemm_mfma(const bf16* __restrict__ A, const bf16* __restrict__ WT,
                                                   const float* __restrict__ bias, void* __restrict__ Y,
                                                   float* __restrict__ part){
  constexpr int NTW = NCOLS/64;           // n-tiles per wave
  int mb = blockIdx.x;
  int tid = threadIdx.x;
  int w = tid >> 6, l = tid & 63, l15 = l & 15, lq = l >> 4;
  f32x4 acc[MT/16][NTW];
  #pragma unroll
  for (int m = 0; m < MT/16; m++)
    #pragma unroll
    for (int nt = 0; nt < NTW; nt++) acc[m][nt] = (f32x4){0.f,0.f,0.f,0.f};
  const bf16* Ab = A + (size_t)mb*MT*K;
  int nw = w*(NCOLS/4);
  for (int s = 0; s < K/32; s++){
    int c0 = s*32 + lq*8;
    bf16x8 bfr[NTW];
    #pragma unroll
    for (int nt = 0; nt < NTW; nt++){
      int fcol = nw + nt*16 + l15;
      bfr[nt] = *reinterpret_cast<const bf16x8*>(WT + (size_t)fcol*K + c0);
    }
    #pragma unroll
    for (int m = 0; m < MT/16; m++){
      bf16x8 afr = *reinterpret_cast<const bf16x8*>(Ab + (size_t)(m*16 + l15)*K + c0);
      #pragma unroll
      for (int nt = 0; nt < NTW; nt++)
        acc[m][nt] = __builtin_amdgcn_mfma_f32_16x16x32_bf16(afr, bfr[nt], acc[m][nt], 0, 0, 0);
    }
  }
  #pragma unroll
  for (int nt = 0; nt < NTW; nt++){
    int fcol = nw + nt*16 + l15;
    float bv = bias[fcol];
    float cs = 0.f, cs2 = 0.f;
    #pragma unroll
    for (int m = 0; m < MT/16; m++){
      #pragma unroll
      for (int v = 0; v < 4; v++){
        int row = mb*MT + m*16 + lq*4 + v;
        float val = acc[m][nt][v] + bv;
        if (ACT == 1) val = fmaxf(val, 0.f);
        else if (ACT == 2) val = eluf(val);
        if (OBF) ((bf16*)Y)[(size_t)row*NCOLS + fcol] = __float2bfloat16(val);
        else     ((float*)Y)[(size_t)row*NCOLS + fcol] = val;
        if (STATS){ cs += val; cs2 += val*val; }
      }
    }
    if (STATS){
      cs  += __shfl_xor(cs, 16);  cs  += __shfl_xor(cs, 32);
      cs2 += __shfl_xor(cs2, 16); cs2 += __shfl_xor(cs2, 32);
      if (l < 16){ part[(size_t)mb*512 + fcol] = cs; part[(size_t)mb*512 + 256 + fcol] = cs2; }
    }
  }
}

// ---------------- edge combiners ----------------
__global__ void combine2(const bf16* __restrict__ SR, bf16* __restrict__ Y){
  int i = blockIdx.x*256 + threadIdx.x;   // 7936*32 chunks
  int row = i >> 5, c8 = (i & 31)*8;
  int b = row / NEDGE, e = row % NEDGE;
  int rc = e / 31, jj = e % 31;
  int sn = jj + (jj >= rc);
  bf16x8 s8 = *reinterpret_cast<const bf16x8*>(SR + (size_t)(b*NNODES + sn)*512 + c8);
  bf16x8 r8 = *reinterpret_cast<const bf16x8*>(SR + (size_t)(b*NNODES + rc)*512 + 256 + c8);
  bf16x8 o;
  #pragma unroll
  for (int k = 0; k < 8; k++){
    float v = bfu2f((unsigned short)s8[k]) + bfu2f((unsigned short)r8[k]);
    v = eluf(v);
    __hip_bfloat16 h = __float2bfloat16(v);
    o[k] = *reinterpret_cast<short*>(&h);
  }
  *reinterpret_cast<bf16x8*>(Y + (size_t)row*256 + c8) = o;
}

__global__ void combine4(const bf16* __restrict__ SR, const float* __restrict__ Z, bf16* __restrict__ Y){
  int i = blockIdx.x*256 + threadIdx.x;
  int row = i >> 5, c8 = (i & 31)*8;
  int b = row / NEDGE, e = row % NEDGE;
  int rc = e / 31, jj = e % 31;
  int sn = jj + (jj >= rc);
  bf16x8 s8 = *reinterpret_cast<const bf16x8*>(SR + (size_t)(b*NNODES + sn)*512 + c8);
  bf16x8 r8 = *reinterpret_cast<const bf16x8*>(SR + (size_t)(b*NNODES + rc)*512 + 256 + c8);
  const float* zp = Z + (size_t)row*256 + c8;
  float4 z0 = *reinterpret_cast<const float4*>(zp);
  float4 z1 = *reinterpret_cast<const float4*>(zp+4);
  float zz[8] = {z0.x,z0.y,z0.z,z0.w,z1.x,z1.y,z1.z,z1.w};
  bf16x8 o;
  #pragma unroll
  for (int k = 0; k < 8; k++){
    float v = bfu2f((unsigned short)s8[k]) + bfu2f((unsigned short)r8[k]) + zz[k];
    v = eluf(v);
    __hip_bfloat16 h = __float2bfloat16(v);
    o[k] = *reinterpret_cast<short*>(&h);
  }
  *reinterpret_cast<bf16x8*>(Y + (size_t)row*256 + c8) = o;
}

// ---------------- batchnorm finalize/apply ----------------
__global__ void bn_finalize(const float* __restrict__ part, int nb, const float* __restrict__ g,
                            const float* __restrict__ be, float* __restrict__ prm, float nrows){
  int f = threadIdx.x;
  float s = 0.f, s2 = 0.f;
  for (int i = 0; i < nb; i++){ s += part[(size_t)i*512+f]; s2 += part[(size_t)i*512+256+f]; }
  float m = s / nrows, var = s2 / nrows - m*m;
  float sc = g[f] * rsqrtf(var + EPSV);
  prm[f] = sc; prm[256+f] = be[f] - m*sc;
}
__global__ void bn_apply(const float* __restrict__ Y, const float* __restrict__ prm, bf16* __restrict__ X){
  int i = blockIdx.x*256 + threadIdx.x;    // 7936*32 chunks of 8
  int c8 = (i & 31)*8;
  const float* yp = Y + (size_t)i*8;
  float4 a0 = *reinterpret_cast<const float4*>(yp);
  float4 a1 = *reinterpret_cast<const float4*>(yp+4);
  float4 s0 = *reinterpret_cast<const float4*>(prm + c8);
  float4 s1 = *reinterpret_cast<const float4*>(prm + c8 + 4);
  float4 h0 = *reinterpret_cast<const float4*>(prm + 256 + c8);
  float4 h1 = *reinterpret_cast<const float4*>(prm + 256 + c8 + 4);
  float vals[8] = {a0.x*s0.x+h0.x, a0.y*s0.y+h0.y, a0.z*s0.z+h0.z, a0.w*s0.w+h0.w,
                   a1.x*s1.x+h1.x, a1.y*s1.y+h1.y, a1.z*s1.z+h1.z, a1.w*s1.w+h1.w};
  bf16x8 o;
  #pragma unroll
  for (int k = 0; k < 8; k++){
    __hip_bfloat16 h = __float2bfloat16(vals[k]);
    o[k] = *reinterpret_cast<short*>(&h);
  }
  *reinterpret_cast<bf16x8*>(X + (size_t)i*8) = o;
}

// ---------------- incoming = segment-sum over 31 edges / N ----------------
__global__ void seg_incoming(const bf16* __restrict__ X2, float* __restrict__ inc){
  int bn = blockIdx.x; int b = bn >> 5, n = bn & 31;
  int f = threadIdx.x;
  const bf16* p = X2 + (size_t)(b*NEDGE + n*31)*256 + f;
  float s = 0.f;
  for (int j = 0; j < 31; j++) s += __bfloat162float(p[j*256]);
  inc[bn*256 + f] = s * (1.f/32.f);
}

// ---------------- fc + softmax (prob out, rel_type to ws) ----------------
__global__ void fc_softmax(const bf16* __restrict__ X4, const float* __restrict__ fcw, const float* __restrict__ fcb,
                           const float* __restrict__ gumbel, float* __restrict__ prob_out, float* __restrict__ rt){
  int r = blockIdx.x*256 + threadIdx.x;
  if (r >= ROWS_E) return;
  float l0 = fcb[0], l1 = fcb[1], l2 = fcb[2], l3 = fcb[3];
  const bf16* xr = X4 + (size_t)r*256;
  for (int c = 0; c < 256; c += 8){
    uint4 u = *reinterpret_cast<const uint4*>(xr + c);
    unsigned uu[4] = {u.x, u.y, u.z, u.w};
    #pragma unroll
    for (int q = 0; q < 4; q++){
      float x0 = bfu2f((unsigned short)(uu[q] & 0xffff));
      float x1 = bfu2f((unsigned short)(uu[q] >> 16));
      int cc = c + 2*q;
      float4 w0 = *reinterpret_cast<const float4*>(fcw + cc*4);
      float4 w1 = *reinterpret_cast<const float4*>(fcw + (cc+1)*4);
      l0 += x0*w0.x + x1*w1.x; l1 += x0*w0.y + x1*w1.y;
      l2 += x0*w0.z + x1*w1.z; l3 += x0*w0.w + x1*w1.w;
    }
  }
  float mx = fmaxf(fmaxf(l0,l1), fmaxf(l2,l3));
  float e0 = __expf(l0-mx), e1 = __expf(l1-mx), e2 = __expf(l2-mx), e3 = __expf(l3-mx);
  float inv = 1.f / (e0+e1+e2+e3);
  prob_out[(size_t)r*4+0] = e0*inv; prob_out[(size_t)r*4+1] = e1*inv;
  prob_out[(size_t)r*4+2] = e2*inv; prob_out[(size_t)r*4+3] = e3*inv;
  float4 gv = *reinterpret_cast<const float4*>(gumbel + (size_t)r*4);
  float t0 = (l0+gv.x)*2.f, t1 = (l1+gv.y)*2.f, t2 = (l2+gv.z)*2.f, t3 = (l3+gv.w)*2.f;
  float mx2 = fmaxf(fmaxf(t0,t1), fmaxf(t2,t3));
  float f0 = __expf(t0-mx2), f1 = __expf(t1-mx2), f2 = __expf(t2-mx2), f3 = __expf(t3-mx2);
  float inv2 = 1.f / (f0+f1+f2+f3);
  rt[(size_t)r*4+0] = f0*inv2; rt[(size_t)r*4+1] = f1*inv2;
  rt[(size_t)r*4+2] = f2*inv2; rt[(size_t)r*4+3] = f3*inv2;
}

// ---------------- fused decoder message passing v4 ----------------
// R1 skeleton (4 receivers, 128 rows, hA 64KB swizzled, wave-owns-4-cols MFMA, B reuse 8x)
// + register-resident S/R layer-1 build (no dynamic reg indexing: unrolled jj loop,
// snd = jj|jj+1 via wave-uniform select between statically-indexed S regs).
__global__ __launch_bounds__(256,2) void decoder_msg(
    const float* __restrict__ data, const float* __restrict__ rt,
    const float* __restrict__ mw1, const float* __restrict__ mb1,
    const bf16* __restrict__ mw2T, const float* __restrict__ mb2,
    bf16* __restrict__ Aaug){
  __shared__ __align__(16) short hA[128*256];   // 64KB, xor-swizzled bf16
  __shared__ __align__(16) float xn[32][4];
  __shared__ __align__(16) float rts_s[128][4];
  __shared__ __align__(16) float aggl[4][256];
  int bx = blockIdx.x;
  int bt = bx >> 3, rg = bx & 7;
  int b = bt / TSTEPS, t = bt % TSTEPS;
  int n0 = rg * 4;
  int tid = threadIdx.x;
  int w = tid >> 6, l = tid & 63, l15 = l & 15, lq = l >> 4;

  if (tid < 32){
    xn[tid][0] = data[((size_t)(b*NNODES + tid)*TSTEPS + t)*4 + 0];
    xn[tid][1] = data[((size_t)(b*NNODES + tid)*TSTEPS + t)*4 + 1];
    xn[tid][2] = data[((size_t)(b*NNODES + tid)*TSTEPS + t)*4 + 2];
    xn[tid][3] = data[((size_t)(b*NNODES + tid)*TSTEPS + t)*4 + 3];
  } else if (tid >= 64 && tid < 192){
    int r = tid - 64;
    int n = n0 + (r >> 5), j = r & 31;
    float4 rv = make_float4(0.f,0.f,0.f,0.f);
    if (j < 31) rv = *reinterpret_cast<const float4*>(rt + ((size_t)(b*NEDGE + n*31 + j))*4);
    *reinterpret_cast<float4*>(&rts_s[r][0]) = rv;
  }
  for (int i = tid; i < 1024; i += 256) ((float*)aggl)[i] = 0.f;
  __syncthreads();

  int p = tid & 127, hf = tid >> 7;      // col pair 2p,2p+1 ; row half hf
  int rc0 = n0 + 2*hf, rc1 = rc0 + 1;    // this thread's two receivers
  int c0b = 4*p;                          // byte offset of col pair

  for (int kk = 1; kk < 4; kk++){
    { // ---- build hA = relu(S[snd] + R[recv]) ----
      float wS0x,wS0y,wS1x,wS1y,wS2x,wS2y,wS3x,wS3y;
      float wR0x,wR0y,wR1x,wR1y,wR2x,wR2y,wR3x,wR3y;
      {
        float2 a0 = *reinterpret_cast<const float2*>(mw1 + (size_t)(kk*8+0)*256 + 2*p);
        float2 a1 = *reinterpret_cast<const float2*>(mw1 + (size_t)(kk*8+1)*256 + 2*p);
        float2 a2 = *reinterpret_cast<const float2*>(mw1 + (size_t)(kk*8+2)*256 + 2*p);
        float2 a3 = *reinterpret_cast<const float2*>(mw1 + (size_t)(kk*8+3)*256 + 2*p);
        float2 a4 = *reinterpret_cast<const float2*>(mw1 + (size_t)(kk*8+4)*256 + 2*p);
        float2 a5 = *reinterpret_cast<const float2*>(mw1 + (size_t)(kk*8+5)*256 + 2*p);
        float2 a6 = *reinterpret_cast<const float2*>(mw1 + (size_t)(kk*8+6)*256 + 2*p);
        float2 a7 = *reinterpret_cast<const float2*>(mw1 + (size_t)(kk*8+7)*256 + 2*p);
        wS0x=a0.x; wS0y=a0.y; wS1x=a1.x; wS1y=a1.y; wS2x=a2.x; wS2y=a2.y; wS3x=a3.x; wS3y=a3.y;
        wR0x=a4.x; wR0y=a4.y; wR1x=a5.x; wR1y=a5.y; wR2x=a6.x; wR2y=a6.y; wR3x=a7.x; wR3y=a7.y;
      }
      float2 bb = *reinterpret_cast<const float2*>(mb1 + kk*256 + 2*p);
      float Sa[32], Sb[32];
      #pragma unroll
      for (int nd = 0; nd < 32; nd++){
        float4 x = *reinterpret_cast<float4*>(&xn[nd][0]);
        Sa[nd] = fmaf(x.x,wS0x, fmaf(x.y,wS1x, fmaf(x.z,wS2x, fmaf(x.w,wS3x, bb.x))));
        Sb[nd] = fmaf(x.x,wS0y, fmaf(x.y,wS1y, fmaf(x.z,wS2y, fmaf(x.w,wS3y, bb.y))));
      }
      float4 x0 = *reinterpret_cast<float4*>(&xn[rc0][0]);
      float4 x1 = *reinterpret_cast<float4*>(&xn[rc1][0]);
      float Ra0 = fmaf(x0.x,wR0x, fmaf(x0.y,wR1x, fmaf(x0.z,wR2x, x0.w*wR3x)));
      float Rb0 = fmaf(x0.x,wR0y, fmaf(x0.y,wR1y, fmaf(x0.z,wR2y, x0.w*wR3y)));
      float Ra1 = fmaf(x1.x,wR0x, fmaf(x1.y,wR1x, fmaf(x1.z,wR2x, x1.w*wR3x)));
      float Rb1 = fmaf(x1.x,wR0y, fmaf(x1.y,wR1y, fmaf(x1.z,wR2y, x1.w*wR3y)));
      char* hAb = reinterpret_cast<char*>(hA);
      #pragma unroll
      for (int jj = 0; jj < 32; jj++){
        { // receiver rc0, row r = hf*64 + jj
          int r = hf*64 + jj;
          unsigned pk = 0u;
          if (jj < 31){
            bool sel = (jj >= rc0);
            float sa = sel ? Sa[jj+1] : Sa[jj];
            float sb = sel ? Sb[jj+1] : Sb[jj];
            pk = pack_bf16(fmaxf(sa + Ra0, 0.f), fmaxf(sb + Rb0, 0.f));
          }
          *reinterpret_cast<unsigned*>(hAb + r*512 + (c0b ^ ((r & 7) << 4))) = pk;
        }
        { // receiver rc1, row r = hf*64 + 32 + jj
          int r = hf*64 + 32 + jj;
          unsigned pk = 0u;
          if (jj < 31){
            bool sel = (jj >= rc1);
            float sa = sel ? Sa[jj+1] : Sa[jj];
            float sb = sel ? Sb[jj+1] : Sb[jj];
            pk = pack_bf16(fmaxf(sa + Ra1, 0.f), fmaxf(sb + Rb1, 0.f));
          }
          *reinterpret_cast<unsigned*>(hAb + r*512 + (c0b ^ ((r & 7) << 4))) = pk;
        }
      }
    }
    __syncthreads();

    // ---- MFMA: wave owns 4 n-tiles (64 cols), loops 8 m-tiles; B reused 8x ----
    f32x4 acc[8][4];
    #pragma unroll
    for (int m = 0; m < 8; m++)
      #pragma unroll
      for (int nt = 0; nt < 4; nt++) acc[m][nt] = (f32x4){0.f,0.f,0.f,0.f};
    const bf16* wk = mw2T + (size_t)kk*65536;
    for (int s = 0; s < 8; s++){
      int c0 = s*32 + lq*8;
      bf16x8 bfr[4];
      #pragma unroll
      for (int nt = 0; nt < 4; nt++){
        int fcol = w*64 + nt*16 + l15;
        bfr[nt] = *reinterpret_cast<const bf16x8*>(wk + (size_t)fcol*256 + c0);
      }
      #pragma unroll
      for (int m = 0; m < 8; m++){
        int rowm = m*16 + l15;
        int byteoff = rowm*512 + ((s*64 + lq*16) ^ ((rowm & 7) << 4));
        bf16x8 af = *reinterpret_cast<const bf16x8*>(reinterpret_cast<const char*>(hA) + byteoff);
        #pragma unroll
        for (int nt = 0; nt < 4; nt++)
          acc[m][nt] = __builtin_amdgcn_mfma_f32_16x16x32_bf16(af, bfr[nt], acc[m][nt], 0, 0, 0);
      }
    }
    // ---- epilogue: relu(+b2) * rel_type, column-reduce into per-receiver agg ----
    #pragma unroll
    for (int m = 0; m < 8; m++){
      int g = m >> 1;
      #pragma unroll
      for (int nt = 0; nt < 4; nt++){
        int fcol = w*64 + nt*16 + l15;
        float bv = mb2[kk*256 + fcol];
        float ssum = 0.f;
        #pragma unroll
        for (int v = 0; v < 4; v++){
          int rowa = m*16 + lq*4 + v;
          float msg = fmaxf(acc[m][nt][v] + bv, 0.f);
          ssum += msg * rts_s[rowa][kk];
        }
        ssum += __shfl_xor(ssum, 16);
        ssum += __shfl_xor(ssum, 32);
        if (lq == 0) aggl[g][fcol] += ssum;
      }
    }
    __syncthreads();
  }

  // write aug rows: [data(4) | agg(256) | pad(28)] bf16, K=288
  for (int i = tid; i < 4*288; i += 256){
    int g = i / 288, c = i % 288;
    float val;
    if (c < 4)        val = xn[n0+g][c];
    else if (c < 260) val = aggl[g][c-4];
    else              val = 0.f;
    Aaug[(size_t)(bt*NNODES + n0 + g)*288 + c] = __float2bfloat16(val);
  }
}

// ---------------- final: p3 = P2 @ ow3 + ob3 ; out = data + p3 (t<48) ----------------
__global__ void final_out(const bf16* __restrict__ P2, const float* __restrict__ ow3,
                          const float* __restrict__ ob3, const float* __restrict__ data,
                          float* __restrict__ out){
  int r = blockIdx.x*256 + threadIdx.x;
  if (r >= ROWS_OUT) return;
  int bt = r >> 5, n = r & 31;
  int b = bt / TSTEPS, t = bt % TSTEPS;
  float a0 = ob3[0], a1 = ob3[1], a2 = ob3[2], a3 = ob3[3];
  const bf16* pr = P2 + (size_t)r*256;
  for (int c = 0; c < 256; c += 8){
    uint4 u = *reinterpret_cast<const uint4*>(pr + c);
    unsigned uu[4] = {u.x, u.y, u.z, u.w};
    #pragma unroll
    for (int q = 0; q < 4; q++){
      float x0 = bfu2f((unsigned short)(uu[q] & 0xffff));
      float x1 = bfu2f((unsigned short)(uu[q] >> 16));
      int cc = c + 2*q;
      float4 w0 = *reinterpret_cast<const float4*>(ow3 + cc*4);
      float4 w1 = *reinterpret_cast<const float4*>(ow3 + (cc+1)*4);
      a0 += x0*w0.x + x1*w1.x; a1 += x0*w0.y + x1*w1.y;
      a2 += x0*w0.z + x1*w1.z; a3 += x0*w0.w + x1*w1.w;
    }
  }
  if (t < TSTEPS-1){
    float4 dv = *reinterpret_cast<const float4*>(data + ((size_t)(b*NNODES + n)*TSTEPS + t)*4);
    float4 o; o.x = dv.x + a0; o.y = dv.y + a1; o.z = dv.z + a2; o.w = dv.w + a3;
    *reinterpret_cast<float4*>(out + ((size_t)(b*NNODES + n)*(TSTEPS-1) + t)*4) = o;
  }
}

// ---------------- launcher ----------------
extern "C" void kernel_launch(void* const* d_in, const int* in_sizes, int n_in,
                              void* d_out, int out_size, void* d_ws, size_t ws_size,
                              hipStream_t stream){
  const float* data    = (const float*)d_in[0];
  const float* gumbel  = (const float*)d_in[1];
  const float* e1_w1=(const float*)d_in[4],  *e1_b1=(const float*)d_in[5],
             * e1_w2=(const float*)d_in[6],  *e1_b2=(const float*)d_in[7],
             * e1_g =(const float*)d_in[8],  *e1_be=(const float*)d_in[9];
  const float* e2_w1=(const float*)d_in[10], *e2_b1=(const float*)d_in[11],
             * e2_w2=(const float*)d_in[12], *e2_b2=(const float*)d_in[13],
             * e2_g =(const float*)d_in[14], *e2_be=(const float*)d_in[15];
  const float* e3_w1=(const float*)d_in[16], *e3_b1=(const float*)d_in[17],
             * e3_w2=(const float*)d_in[18], *e3_b2=(const float*)d_in[19],
             * e3_g =(const float*)d_in[20], *e3_be=(const float*)d_in[21];
  const float* e4_w1=(const float*)d_in[22], *e4_b1=(const float*)d_in[23],
             * e4_w2=(const float*)d_in[24], *e4_b2=(const float*)d_in[25],
             * e4_g =(const float*)d_in[26], *e4_be=(const float*)d_in[27];
  const float* fc_w=(const float*)d_in[28], *fc_b=(const float*)d_in[29];
  const float* mw1=(const float*)d_in[30], *mb1=(const float*)d_in[31];
  const float* mw2=(const float*)d_in[32], *mb2=(const float*)d_in[33];
  const float* ow1=(const float*)d_in[34], *ob1=(const float*)d_in[35];
  const float* ow2=(const float*)d_in[36], *ob2=(const float*)d_in[37];
  const float* ow3=(const float*)d_in[38], *ob3=(const float*)d_in[39];

  char* ws = (char*)d_ws;
  size_t off = 0;
  auto alloc = [&](size_t bytes)->void*{ void* p = ws + off; off = (off + bytes + 255) & ~(size_t)255; return p; };
  bf16* W2ABT= (bf16*)alloc((size_t)131072*2);
  bf16* W2BT = (bf16*)alloc((size_t)65536*2);
  bf16* W4ABT= (bf16*)alloc((size_t)131072*2);
  bf16* W4CT = (bf16*)alloc((size_t)65536*2);
  bf16* W4BT = (bf16*)alloc((size_t)65536*2);
  bf16* MW2T = (bf16*)alloc((size_t)262144*2);
  bf16* OW1T = (bf16*)alloc((size_t)73728*2);
  bf16* OW2T = (bf16*)alloc((size_t)65536*2);
  float* BIAS2=(float*)alloc((size_t)512*4);
  float* BIAS4=(float*)alloc((size_t)512*4);
  float* ZEROB=(float*)alloc((size_t)256*4);
  bf16* X1   = (bf16*)alloc((size_t)65536*2);
  float* HS  = (float*)alloc((size_t)65536*4);
  bf16* X3   = (bf16*)alloc((size_t)65536*2);
  bf16* SR2  = (bf16*)alloc((size_t)131072*2);
  bf16* SR4  = (bf16*)alloc((size_t)131072*2);
  float* Z4  = (float*)alloc((size_t)7936*256*4);
  bf16* YBF  = (bf16*)alloc((size_t)12544*256*2);
  float* YF32= (float*)alloc((size_t)7936*256*4);
  bf16* X2   = (bf16*)alloc((size_t)7936*256*2);
  bf16* X4   = (bf16*)alloc((size_t)7936*256*2);
  bf16* P2   = (bf16*)alloc((size_t)12544*256*2);
  float* INC = (float*)alloc((size_t)65536*4);
  float* RT  = (float*)alloc((size_t)7936*4*4);
  float* PART= (float*)alloc((size_t)248*512*4);
  float* PRM = (float*)alloc((size_t)512*4);
  bf16* AAUG = (bf16*)alloc((size_t)12544*288*2);

  float* out = (float*)d_out;
  float* prob_out = out + 49152;

  prep_weights<<<3365,256,0,stream>>>(e2_w1,e2_w2,e4_w1,e4_w2,mw2,ow1,ow2,e2_b1,e4_b1,
                                      W2ABT,W2BT,W4ABT,W4CT,W4BT,MW2T,OW1T,OW2T,BIAS2,BIAS4,ZEROB);
  small_mlp<196><<<256,256,0,stream>>>(data, e1_w1,e1_b1,e1_w2,e1_b2, HS);
  bn_small<<<1,256,0,stream>>>(HS, e1_g, e1_be, X1);
  gemm_mfma<256,512,0,true,32,false><<<8,256,0,stream>>>(X1, W2ABT, BIAS2, SR2, nullptr);
  combine2<<<992,256,0,stream>>>(SR2, YBF);
  gemm_mfma<256,256,2,false,32,true><<<248,256,0,stream>>>(YBF, W2BT, e2_b2, YF32, PART);
  bn_finalize<<<1,256,0,stream>>>(PART, 248, e2_g, e2_be, PRM, 7936.f);
  bn_apply<<<992,256,0,stream>>>(YF32, PRM, X2);
  seg_incoming<<<256,256,0,stream>>>(X2, INC);
  small_mlp<256><<<256,256,0,stream>>>(INC, e3_w1,e3_b1,e3_w2,e3_b2, HS);
  bn_small<<<1,256,0,stream>>>(HS, e3_g, e3_be, X3);
  gemm_mfma<256,512,0,true,32,false><<<8,256,0,stream>>>(X3, W4ABT, BIAS4, SR4, nullptr);
  gemm_mfma<256,256,0,false,32,false><<<248,256,0,stream>>>(X2, W4CT, ZEROB, Z4, nullptr);
  combine4<<<992,256,0,stream>>>(SR4, Z4, YBF);
  gemm_mfma<256,256,2,false,32,true><<<248,256,0,stream>>>(YBF, W4BT, e4_b2, YF32, PART);
  bn_finalize<<<1,256,0,stream>>>(PART, 248, e4_g, e4_be, PRM, 7936.f);
  bn_apply<<<992,256,0,stream>>>(YF32, PRM, X4);
  fc_softmax<<<31,256,0,stream>>>(X4, fc_w, fc_b, gumbel, prob_out, RT);
  decoder_msg<<<3136,256,0,stream>>>(data, RT, mw1, mb1, MW2T, mb2, AAUG);
  gemm_mfma<288,256,1,true,32,false><<<392,256,0,stream>>>(AAUG, OW1T, ob1, YBF, nullptr);
  gemm_mfma<256,256,1,true,32,false><<<392,256,0,stream>>>(YBF, OW2T, ob2, P2, nullptr);
  final_out<<<49,256,0,stream>>>(P2, ow3, ob3, data, out);
}